// Round 3
// baseline (450.000 us; speedup 1.0000x reference)
//
#include <hip/hip_runtime.h>

// Nearest-qpoint quantize, bit-exact vs the numpy reference:
//   idx = searchsorted(q, x); lo = q[clip(idx-1,0,15)]; hi = q[clip(idx,0,15)]
//   out = |x-lo| <= |x-hi| ? lo : hi
//
// R2: replace the two 15-step compare-select chains (~64 VALU ops/elem) with a
// single 15-threshold thermometer chain (~30 VALU ops/elem). The decision
// boundary t_k = max{ x : |x-q[k]| <= |x-q[k+1]| } is found EXACTLY by a tiny
// setup kernel (bisection in ordered-bit space using the reference's own fp32
// predicate), so no midpoint-rounding mismatch is possible. t_k are strictly
// increasing => r = (x > t_k) ? q[k+1] : r reproduces the reference bit-exactly
// for every fp32 x (ties included). Nontemporal hints: pure streaming, 0 reuse.
//
// R4 fix: __builtin_nontemporal_load/store requires a NATIVE clang vector type,
// not HIP_vector_type<float,4>. Use ext_vector_type(4) (same 16B layout, still
// emits global_load/store_dwordx4) and reinterpret_cast the pointers.

typedef float f32x4 __attribute__((ext_vector_type(4)));

__device__ __forceinline__ float rfl(float v) {
    return __int_as_float(__builtin_amdgcn_readfirstlane(__float_as_int(v)));
}

// Monotone float <-> ordered-uint bijection (finite range only, which holds:
// qpoints are in [-1.5, 1.5]).
__device__ __forceinline__ unsigned f2o(float f) {
    unsigned b = __float_as_uint(f);
    return (b & 0x80000000u) ? ~b : (b | 0x80000000u);
}
__device__ __forceinline__ float o2f(unsigned o) {
    unsigned b = (o & 0x80000000u) ? (o ^ 0x80000000u) : ~o;
    return __uint_as_float(b);
}

// Setup: for each adjacent pair, bisect for the largest fp32 t with
// D(t) = |t-lo| <= |t-hi| (computed with the exact reference fp32 ops).
// D is monotone non-increasing in t, true at lo, false at hi.
__global__ void qthresh_setup(const float* __restrict__ q,
                              float* __restrict__ t) {
    int k = threadIdx.x;
    if (k > 15) return;
    if (k == 15) { t[15] = __uint_as_float(0x7f800000u); return; }  // pad
    float lo = q[k], hi = q[k + 1];
    unsigned a = f2o(lo), b = f2o(hi);
    while (b - a > 1u) {
        unsigned m = a + ((b - a) >> 1);
        float xm = o2f(m);
        if (fabsf(xm - lo) <= fabsf(xm - hi)) a = m; else b = m;
    }
    t[k] = o2f(a);
}

__device__ __forceinline__ float chain16(float xv, const float qp[16],
                                         const float th[15]) {
    float r = qp[0];
#pragma unroll
    for (int k = 0; k < 15; ++k) r = (xv > th[k]) ? qp[k + 1] : r;
    return r;
}

__global__ __launch_bounds__(256) void qquant_chain(
    const f32x4* __restrict__ x, const float* __restrict__ q,
    const float* __restrict__ t, f32x4* __restrict__ out, int n4) {
    // One-time table load: 8 VMEM ops, then pin to SGPRs via readfirstlane.
    const f32x4* q4 = (const f32x4*)q;
    const f32x4* t4 = (const f32x4*)t;
    f32x4 qa = q4[0], qb = q4[1], qc = q4[2], qd = q4[3];
    f32x4 ta = t4[0], tb = t4[1], tc = t4[2], td = t4[3];
    float qp[16] = {rfl(qa.x), rfl(qa.y), rfl(qa.z), rfl(qa.w),
                    rfl(qb.x), rfl(qb.y), rfl(qb.z), rfl(qb.w),
                    rfl(qc.x), rfl(qc.y), rfl(qc.z), rfl(qc.w),
                    rfl(qd.x), rfl(qd.y), rfl(qd.z), rfl(qd.w)};
    float th[15] = {rfl(ta.x), rfl(ta.y), rfl(ta.z), rfl(ta.w),
                    rfl(tb.x), rfl(tb.y), rfl(tb.z), rfl(tb.w),
                    rfl(tc.x), rfl(tc.y), rfl(tc.z), rfl(tc.w),
                    rfl(td.x), rfl(td.y), rfl(td.z)};

    int stride = gridDim.x * blockDim.x;
    for (int i = blockIdx.x * blockDim.x + threadIdx.x; i < n4; i += stride) {
        f32x4 v = __builtin_nontemporal_load(&x[i]);
        f32x4 r;
        r.x = chain16(v.x, qp, th);
        r.y = chain16(v.y, qp, th);
        r.z = chain16(v.z, qp, th);
        r.w = chain16(v.w, qp, th);
        __builtin_nontemporal_store(r, &out[i]);
    }
}

// ---- fallback path (no workspace): R1 kernel, known-good at 443us ----
__device__ __forceinline__ float quant1(float xv, const float qp[16]) {
    float hi = qp[15];
#pragma unroll
    for (int k = 14; k >= 0; --k) hi = (qp[k] >= xv) ? qp[k] : hi;
    float lo = qp[0];
#pragma unroll
    for (int k = 1; k < 16; ++k) lo = (qp[k] < xv) ? qp[k] : lo;
    return (fabsf(xv - lo) <= fabsf(xv - hi)) ? lo : hi;
}

__global__ __launch_bounds__(256) void qquant_vec4(
    const float4* __restrict__ x, const float* __restrict__ q,
    float4* __restrict__ out, int n4) {
    const float4* q4 = (const float4*)q;
    float4 q0 = q4[0], q1 = q4[1], q2 = q4[2], q3 = q4[3];
    float qp[16] = {rfl(q0.x), rfl(q0.y), rfl(q0.z), rfl(q0.w),
                    rfl(q1.x), rfl(q1.y), rfl(q1.z), rfl(q1.w),
                    rfl(q2.x), rfl(q2.y), rfl(q2.z), rfl(q2.w),
                    rfl(q3.x), rfl(q3.y), rfl(q3.z), rfl(q3.w)};
    int stride = gridDim.x * blockDim.x;
    for (int i = blockIdx.x * blockDim.x + threadIdx.x; i < n4; i += stride) {
        float4 v = x[i];
        float4 r;
        r.x = quant1(v.x, qp);
        r.y = quant1(v.y, qp);
        r.z = quant1(v.z, qp);
        r.w = quant1(v.w, qp);
        out[i] = r;
    }
}

__global__ void qquant_tail(const float* __restrict__ x,
                            const float* __restrict__ q,
                            float* __restrict__ out, int start, int n) {
    int i = start + threadIdx.x;
    if (i >= n) return;
    float qp[16];
#pragma unroll
    for (int k = 0; k < 16; ++k) qp[k] = q[k];
    out[i] = quant1(x[i], qp);
}

extern "C" void kernel_launch(void* const* d_in, const int* in_sizes, int n_in,
                              void* d_out, int out_size, void* d_ws, size_t ws_size,
                              hipStream_t stream) {
    const float* x = (const float*)d_in[0];
    const float* q = (const float*)d_in[1];
    float* out = (float*)d_out;
    int n = in_sizes[0];

    int n4 = n >> 2;
    // Host-side branch on constant (ws_size) -> graph-capture safe.
    bool use_ws = (d_ws != nullptr) && (ws_size >= 16 * sizeof(float));
    if (n4 > 0) {
        int blocks = (n4 + 255) / 256;
        if (blocks > 8192) blocks = 8192;
        if (use_ws) {
            float* t = (float*)d_ws;
            qthresh_setup<<<1, 64, 0, stream>>>(q, t);
            qquant_chain<<<blocks, 256, 0, stream>>>((const f32x4*)x, q, t,
                                                     (f32x4*)out, n4);
        } else {
            qquant_vec4<<<blocks, 256, 0, stream>>>((const float4*)x, q,
                                                    (float4*)out, n4);
        }
    }
    int rem = n & 3;
    if (rem > 0) {
        qquant_tail<<<1, 64, 0, stream>>>(x, q, out, n4 << 2, n);
    }
}